// Round 6
// baseline (6458.994 us; speedup 1.0000x reference)
//
#include <hip/hip_runtime.h>
#include <hip/hip_bf16.h>

// ---- problem constants ----
#define T_TOK 2048
#define HID   1024
#define FF    1024
#define NEXP  8
#define NPAIR 4096

// ---- tiling: per-wave 64x64 MFMA tile, 4-wave blocks, NO LDS / NO barriers ----
#define BM 128
#define MAX_MT 40
#define MAXROWS (MAX_MT*BM)   // 5120
#define PPT (NPAIR/256)       // 16
#define NPREP 1024
#define NCVT 256              // wdn-convert blocks embedded in GEMM1 launch

using bf16x8 = __attribute__((ext_vector_type(8))) __bf16;
using us8    = __attribute__((ext_vector_type(8))) unsigned short;
using f32x4  = __attribute__((ext_vector_type(4))) float;

__device__ __forceinline__ unsigned short f2bf(float f) {
    unsigned int u = __float_as_uint(f);
    return (unsigned short)((u + 0x7FFF + ((u >> 16) & 1)) >> 16);   // RNE
}
__device__ __forceinline__ float bf2f(unsigned short s) {
    return __uint_as_float(((unsigned int)s) << 16);
}
__device__ __forceinline__ us8 cvt8(float4 x, float4 y) {
    us8 o;
    o[0] = f2bf(x.x); o[1] = f2bf(x.y); o[2] = f2bf(x.z); o[3] = f2bf(x.w);
    o[4] = f2bf(y.x); o[5] = f2bf(y.y); o[6] = f2bf(y.z); o[7] = f2bf(y.w);
    return o;
}

// ---------------- prep: wgu + hs fp32->bf16; block NPREP does the expert scan ----
__global__ void prep_kernel(const float* __restrict__ wgu,
                            const float* __restrict__ hs,
                            const int* __restrict__ ids,
                            int* __restrict__ pair_pos,
                            int* __restrict__ row_tok,
                            int* __restrict__ meta,
                            unsigned short* __restrict__ wgu_b,
                            unsigned short* __restrict__ hs_b) {
    int tid = threadIdx.x;
    if (blockIdx.x == NPREP) {
        __shared__ int S[2][256][NEXP];
        __shared__ int base[NEXP];
        int myc[NEXP];
        int eloc[PPT];
#pragma unroll
        for (int e = 0; e < NEXP; e++) myc[e] = 0;
#pragma unroll
        for (int i = 0; i < PPT; i++) {
            int e = ids[tid * PPT + i];
            eloc[i] = e;
#pragma unroll
            for (int ee = 0; ee < NEXP; ee++) myc[ee] += (e == ee);
        }
#pragma unroll
        for (int e = 0; e < NEXP; e++) S[0][tid][e] = myc[e];
        __syncthreads();
        int src = 0;
        for (int d = 1; d < 256; d <<= 1) {
#pragma unroll
            for (int e = 0; e < NEXP; e++) {
                int v = S[src][tid][e];
                if (tid >= d) v += S[src][tid - d][e];
                S[src ^ 1][tid][e] = v;
            }
            __syncthreads();
            src ^= 1;
        }
        if (tid == 0) {
            int mt = 0;
            for (int e = 0; e < NEXP; e++) {
                meta[e] = mt;
                base[e] = mt * BM;
                mt += (S[src][255][e] + BM - 1) / BM;
            }
            meta[NEXP] = mt;
        }
        for (int i = tid; i < MAXROWS; i += 256) row_tok[i] = -1;
        __syncthreads();
        int off[NEXP];
#pragma unroll
        for (int e = 0; e < NEXP; e++) off[e] = base[e] + S[src][tid][e] - myc[e];
#pragma unroll
        for (int i = 0; i < PPT; i++) {
            int p = tid * PPT + i;
            int e = eloc[i];
            int pos = 0;
#pragma unroll
            for (int ee = 0; ee < NEXP; ee++) if (e == ee) pos = off[ee]++;
            pair_pos[p] = pos;
            row_tok[pos] = p >> 1;
        }
        return;
    }
    long stride = (long)NPREP * 256;
    long t0 = (long)blockIdx.x * 256 + tid;
    const long N8 = (long)NEXP * 2 * FF * HID / 8;   // wgu: 2.1M ushort8
    for (long i = t0; i < N8; i += stride) {
        float4 x = ((const float4*)wgu)[2 * i];
        float4 y = ((const float4*)wgu)[2 * i + 1];
        ((us8*)wgu_b)[i] = cvt8(x, y);
    }
    const long NH8 = (long)T_TOK * HID / 8;
    for (long i = t0; i < NH8; i += stride) {
        float4 x = ((const float4*)hs)[2 * i];
        float4 y = ((const float4*)hs)[2 * i + 1];
        ((us8*)hs_b)[i] = cvt8(x, y);
    }
}

// ---------------- grouped GEMM: barrier-free, direct global->VGPR->MFMA ----------
// Per-wave 64x64 tile. A,B fragments loaded straight from global (L1/L2-served),
// prefetch-1 double-buffered in registers. No LDS, no __syncthreads in K-loop.
// EPI==1: A rows indirect via row_tok into hs_b; B rows de-interleave gate/up at
//         pointer setup; first NCVT blocks instead convert wdn fp32->bf16.
// EPI==2: A = act (bucket-ordered); plain bf16 store.
template<int EPI, int NBY>
__global__ __launch_bounds__(256)
void gemm_moe(const unsigned short* __restrict__ A,
              const unsigned short* __restrict__ B,
              unsigned short* __restrict__ Cbf,
              const int* __restrict__ meta,
              const int* __restrict__ row_tok,
              int K, long Bexp,
              const float* __restrict__ wdn_src,
              unsigned short* __restrict__ wdn_dst) {
    int L = blockIdx.x;
    int tid = threadIdx.x;
    if (EPI == 1) {
        if (L < NCVT) {     // hidden wdn conversion under GEMM1
            long stride = (long)NCVT * 256;
            const long N8 = (long)NEXP * HID * FF / 8;
            for (long i = (long)L * 256 + tid; i < N8; i += stride) {
                float4 x = ((const float4*)wdn_src)[2 * i];
                float4 y = ((const float4*)wdn_src)[2 * i + 1];
                ((us8*)wdn_dst)[i] = cvt8(x, y);
            }
            return;
        }
        L -= NCVT;
    }
    // XCD-locality: xcd = L%8 owns NBY/8 consecutive n-slabs across all bx
    int xcd = L & 7;
    int slot = L >> 3;
    constexpr int PER = NBY / 8;
    int by = xcd * PER + (slot % PER);
    int bx = slot / PER;
    if (bx >= meta[NEXP]) return;
    int e = 0;
#pragma unroll
    for (int i = 1; i < NEXP; i++) if (bx >= meta[i]) e = i;

    long m0 = (long)bx * BM;
    int n0 = by * 128;

    int lane = tid & 63, wv = tid >> 6;
    const int r = lane & 15;
    const int q = lane >> 4;
    const int mw = (wv >> 1) * 64, nw = (wv & 1) * 64;

    // per-lane fragment pointers; +q*8 selects this lane's 16B chunk of the row
    const unsigned short* pa[4];
    const unsigned short* pb[4];
#pragma unroll
    for (int i = 0; i < 4; i++) {
        long row;
        if (EPI == 1) {
            int tk = row_tok[m0 + mw + i * 16 + r];
            if (tk < 0) tk = 0;               // pad rows: garbage in, never read out
            row = tk;
        } else {
            row = m0 + mw + i * 16 + r;
        }
        pa[i] = A + row * (long)K + q * 8;
    }
#pragma unroll
    for (int j = 0; j < 4; j++) {
        int n = n0 + nw + j * 16 + r;
        long grow;
        if (EPI == 1) grow = ((n & 1) ? FF : 0) + (n >> 1);   // even=gate, odd=up
        else          grow = n;
        pb[j] = B + (long)e * Bexp + grow * (long)K + q * 8;
    }

    f32x4 acc[4][4] = {};
    bf16x8 af[2][4], bfv[2][4];
    const int NKI = K / 32;
#pragma unroll
    for (int i = 0; i < 4; i++) af[0][i] = *(const bf16x8*)(pa[i]);
#pragma unroll
    for (int j = 0; j < 4; j++) bfv[0][j] = *(const bf16x8*)(pb[j]);
    for (int ki = 0; ki < NKI; ki++) {
        int s = ki & 1;
        if (ki + 1 < NKI) {
            int k0 = (ki + 1) * 32;
#pragma unroll
            for (int i = 0; i < 4; i++) af[s ^ 1][i] = *(const bf16x8*)(pa[i] + k0);
#pragma unroll
            for (int j = 0; j < 4; j++) bfv[s ^ 1][j] = *(const bf16x8*)(pb[j] + k0);
        }
#pragma unroll
        for (int i = 0; i < 4; i++)
#pragma unroll
            for (int j = 0; j < 4; j++)
                acc[i][j] = __builtin_amdgcn_mfma_f32_16x16x32_bf16(af[s][i], bfv[s][j], acc[i][j], 0, 0, 0);
    }

    // D layout: row = q*4 + reg, col = lane&15 per 16x16 tile
    if (EPI == 1) {
#pragma unroll
        for (int i = 0; i < 4; i++) {
            long rowb = m0 + mw + i * 16 + q * 4;
#pragma unroll
            for (int j = 0; j < 4; j++) {
                int n = n0 + nw + j * 16 + r;
#pragma unroll
                for (int reg = 0; reg < 4; reg++) {
                    float v = acc[i][j][reg];
                    float o = __shfl_xor(v, 1);
                    if (!(r & 1)) {
                        float g = v, u = o;
                        float s2 = g / (1.f + __expf(-g)) * u;
                        Cbf[(rowb + reg) * (long)FF + (n >> 1)] = f2bf(s2);
                    }
                }
            }
        }
    } else {
#pragma unroll
        for (int i = 0; i < 4; i++) {
            long rowb = m0 + mw + i * 16 + q * 4;
#pragma unroll
            for (int j = 0; j < 4; j++) {
                int n = n0 + nw + j * 16 + r;
#pragma unroll
                for (int reg = 0; reg < 4; reg++)
                    Cbf[(rowb + reg) * (long)HID + n] = f2bf(acc[i][j][reg]);
            }
        }
    }
}

// ---------------- weighted combine ----------------
__global__ void combine_kernel(const unsigned short* __restrict__ y,
                               const float* __restrict__ tw,
                               const int* __restrict__ pair_pos,
                               float* __restrict__ out) {
    int t = blockIdx.x;
    int c = threadIdx.x * 4;
    int p0 = pair_pos[t * 2], p1 = pair_pos[t * 2 + 1];
    float w0 = tw[t * 2], w1 = tw[t * 2 + 1];
    ushort4 a = *(const ushort4*)(y + (long)p0 * HID + c);
    ushort4 b = *(const ushort4*)(y + (long)p1 * HID + c);
    float4 o;
    o.x = w0 * bf2f(a.x) + w1 * bf2f(b.x);
    o.y = w0 * bf2f(a.y) + w1 * bf2f(b.y);
    o.z = w0 * bf2f(a.z) + w1 * bf2f(b.z);
    o.w = w0 * bf2f(a.w) + w1 * bf2f(b.w);
    *(float4*)(out + (long)t * HID + c) = o;
}

extern "C" void kernel_launch(void* const* d_in, const int* in_sizes, int n_in,
                              void* d_out, int out_size, void* d_ws, size_t ws_size,
                              hipStream_t stream) {
    const float* hs  = (const float*)d_in[0];
    const float* tw  = (const float*)d_in[1];
    const int*   ids = (const int*)d_in[2];
    const float* wgu = (const float*)d_in[3];
    const float* wdn = (const float*)d_in[4];
    float* out = (float*)d_out;

    char* ws = (char*)d_ws;
    size_t off = 0;
    auto alloc = [&](size_t bytes) -> void* {
        void* p = ws + off;
        off += (bytes + 255) & ~(size_t)255;
        return p;
    };
    unsigned short* wgu_b = (unsigned short*)alloc((size_t)NEXP * 2 * FF * HID * 2); // 32 MB
    unsigned short* wdn_b = (unsigned short*)alloc((size_t)NEXP * HID * FF * 2);     // 16 MB
    unsigned short* hs_b  = (unsigned short*)alloc((size_t)T_TOK * HID * 2);         // 4 MB
    unsigned short* act   = (unsigned short*)alloc((size_t)MAXROWS * FF * 2);        // 10 MB
    unsigned short* ybuf  = (unsigned short*)alloc((size_t)MAXROWS * HID * 2);       // 10 MB
    int* pair_pos = (int*)alloc(NPAIR * 4);
    int* row_tok  = (int*)alloc(MAXROWS * 4);
    int* meta     = (int*)alloc(64);

    prep_kernel<<<NPREP + 1, 256, 0, stream>>>(wgu, hs, ids, pair_pos, row_tok, meta,
                                               wgu_b, hs_b);

    // GEMM1 (+ embedded wdn conversion): (rows x1024) x wgu_e(2048x1024)^T -> silu -> act
    gemm_moe<1, 16><<<NCVT + 16 * MAX_MT, 256, 0, stream>>>(
        hs_b, wgu_b, act, meta, row_tok, HID, (long)(2 * FF) * HID, wdn, wdn_b);

    // GEMM2: (rows x 1024) x wdn_e(1024 x 1024)^T -> ybuf bf16
    gemm_moe<2, 8><<<8 * MAX_MT, 256, 0, stream>>>(
        act, wdn_b, ybuf, meta, row_tok, FF, (long)HID * FF, nullptr, nullptr);

    combine_kernel<<<T_TOK, 256, 0, stream>>>(ybuf, tw, pair_pos, out);
}

// Round 7
// 211.486 us; speedup vs baseline: 30.5411x; 30.5411x over previous
//
#include <hip/hip_runtime.h>
#include <hip/hip_bf16.h>

// ---- problem constants ----
#define T_TOK 2048
#define HID   1024
#define FF    1024
#define NEXP  8
#define NPAIR 4096

// ---- tiling ----
#define BM 128
#define BK 32
#define MAX_MT 40
#define MAXROWS (MAX_MT*BM)   // 5120
#define PPT (NPAIR/256)       // 16
#define NPREP 4096
#define NCVT 128              // wdn-convert blocks embedded in GEMM1 launch

using bf16x8 = __attribute__((ext_vector_type(8))) __bf16;
using us8    = __attribute__((ext_vector_type(8))) unsigned short;
using f32x4  = __attribute__((ext_vector_type(4))) float;

__device__ __forceinline__ unsigned short f2bf(float f) {
    unsigned int u = __float_as_uint(f);
    return (unsigned short)((u + 0x7FFF + ((u >> 16) & 1)) >> 16);   // RNE
}
__device__ __forceinline__ float bf2f(unsigned short s) {
    return __uint_as_float(((unsigned int)s) << 16);
}
__device__ __forceinline__ us8 cvt8(float4 x, float4 y) {
    us8 o;
    o[0] = f2bf(x.x); o[1] = f2bf(x.y); o[2] = f2bf(x.z); o[3] = f2bf(x.w);
    o[4] = f2bf(y.x); o[5] = f2bf(y.y); o[6] = f2bf(y.z); o[7] = f2bf(y.w);
    return o;
}
__device__ __forceinline__ void gll16(const unsigned short* g, unsigned short* l) {
    __builtin_amdgcn_global_load_lds(
        (const __attribute__((address_space(1))) void*)(const void*)g,
        (__attribute__((address_space(3))) void*)(void*)l, 16, 0, 0);
}

// ---------------- prep: wgu + hs fp32->bf16; block NPREP does the expert scan ----
__global__ void prep_kernel(const float* __restrict__ wgu,
                            const float* __restrict__ hs,
                            const int* __restrict__ ids,
                            int* __restrict__ pair_pos,
                            int* __restrict__ row_tok,
                            int* __restrict__ meta,
                            unsigned short* __restrict__ wgu_b,
                            unsigned short* __restrict__ hs_b) {
    int tid = threadIdx.x;
    if (blockIdx.x == NPREP) {
        __shared__ int S[2][256][NEXP];
        __shared__ int base[NEXP];
        int myc[NEXP];
        int eloc[PPT];
#pragma unroll
        for (int e = 0; e < NEXP; e++) myc[e] = 0;
#pragma unroll
        for (int i = 0; i < PPT; i++) {
            int e = ids[tid * PPT + i];
            eloc[i] = e;
#pragma unroll
            for (int ee = 0; ee < NEXP; ee++) myc[ee] += (e == ee);
        }
#pragma unroll
        for (int e = 0; e < NEXP; e++) S[0][tid][e] = myc[e];
        __syncthreads();
        int src = 0;
        for (int d = 1; d < 256; d <<= 1) {
#pragma unroll
            for (int e = 0; e < NEXP; e++) {
                int v = S[src][tid][e];
                if (tid >= d) v += S[src][tid - d][e];
                S[src ^ 1][tid][e] = v;
            }
            __syncthreads();
            src ^= 1;
        }
        if (tid == 0) {
            int mt = 0;
            for (int e = 0; e < NEXP; e++) {
                meta[e] = mt;
                base[e] = mt * BM;
                mt += (S[src][255][e] + BM - 1) / BM;
            }
            meta[NEXP] = mt;
        }
        for (int i = tid; i < MAXROWS; i += 256) row_tok[i] = -1;
        __syncthreads();
        int off[NEXP];
#pragma unroll
        for (int e = 0; e < NEXP; e++) off[e] = base[e] + S[src][tid][e] - myc[e];
#pragma unroll
        for (int i = 0; i < PPT; i++) {
            int p = tid * PPT + i;
            int e = eloc[i];
            int pos = 0;
#pragma unroll
            for (int ee = 0; ee < NEXP; ee++) if (e == ee) pos = off[ee]++;
            pair_pos[p] = pos;
            row_tok[pos] = p >> 1;
        }
        return;
    }
    long stride = (long)NPREP * 256;
    long t0 = (long)blockIdx.x * 256 + tid;
    const long N8 = (long)NEXP * 2 * FF * HID / 8;   // wgu
    for (long i = t0; i < N8; i += stride) {
        float4 x = ((const float4*)wgu)[2 * i];
        float4 y = ((const float4*)wgu)[2 * i + 1];
        ((us8*)wgu_b)[i] = cvt8(x, y);
    }
    const long NH8 = (long)T_TOK * HID / 8;
    for (long i = t0; i < NH8; i += stride) {
        float4 x = ((const float4*)hs)[2 * i];
        float4 y = ((const float4*)hs)[2 * i + 1];
        ((us8*)hs_b)[i] = cvt8(x, y);
    }
}

// ---------------- grouped GEMM: gll16-staged, big-N tiles, XCD-pinned slabs ----------
// EPI==1: BN=256. A rows indirect via row_tok into hs_b; B rows de-interleave
//         gate/up at pointer setup; first NCVT blocks convert wdn fp32->bf16.
//         Epilogue silu(gate)*up -> act bf16 (FF cols).
// EPI==2: BN=128. A = act (bucket-ordered); plain bf16 store to ybuf.
template<int EPI, int BN_>
__global__ __launch_bounds__(256, 2)
void gemm_moe(const unsigned short* __restrict__ A,
              const unsigned short* __restrict__ B,
              unsigned short* __restrict__ Cbf,
              const int* __restrict__ meta,
              const int* __restrict__ row_tok,
              int K, long Bexp,
              const float* __restrict__ wdn_src,
              unsigned short* __restrict__ wdn_dst) {
    __shared__ unsigned short As[2][BM * BK];    // 16 KB
    __shared__ unsigned short Bs[2][BN_ * BK];   // 32 KB (BN=256) / 16 KB (BN=128)

    int L = blockIdx.x;
    int tid = threadIdx.x;
    if (EPI == 1) {
        if (L < NCVT) {     // hidden wdn conversion under GEMM1
            long stride = (long)NCVT * 256;
            const long N8 = (long)NEXP * HID * FF / 8;
            for (long i = (long)L * 256 + tid; i < N8; i += stride) {
                float4 x = ((const float4*)wdn_src)[2 * i];
                float4 y = ((const float4*)wdn_src)[2 * i + 1];
                ((us8*)wdn_dst)[i] = cvt8(x, y);
            }
            return;
        }
        L -= NCVT;
    }
    // 8 n-slabs <-> 8 XCDs: slab by pinned to xcd = L&7
    int by = L & 7;
    int bx = L >> 3;
    if (bx >= meta[NEXP]) return;
    int e = 0;
#pragma unroll
    for (int i = 1; i < NEXP; i++) if (bx >= meta[i]) e = i;

    long m0 = (long)bx * BM;
    int n0 = by * BN_;

    int lane = tid & 63, wv = tid >> 6;
    const int r = lane & 15;
    const int q = lane >> 4;
    const int mw = (wv >> 1) * 64, nw = (wv & 1) * (BN_ / 2);
    const int sw = (q ^ ((r >> 1) & 3)) * 8;   // swizzled k-chunk for frag reads
    constexpr int NJ = BN_ / 32;               // b-frags per wave
    constexpr int BCH = BN_ * 4 / 256;         // B chunks per thread

    // per-thread staging source pointers (rows fixed across K)
    const unsigned short* ap[2];
#pragma unroll
    for (int h = 0; h < 2; h++) {
        int c = h * 256 + tid;
        int row = c >> 2, cp = c & 3;
        int cc = cp ^ ((row >> 1) & 3);
        long grow;
        if (EPI == 1) {
            int tk = row_tok[m0 + row];
            if (tk < 0) tk = 0;               // pad rows: garbage in, never read out
            grow = tk;
        } else {
            grow = m0 + row;
        }
        ap[h] = A + grow * (long)K + cc * 8;
    }
    const unsigned short* bp[BCH];
#pragma unroll
    for (int h = 0; h < BCH; h++) {
        int c = h * 256 + tid;
        int row = c >> 2, cp = c & 3;
        int cc = cp ^ ((row >> 1) & 3);
        long grow;
        if (EPI == 1) {
            int n = n0 + row;
            grow = ((n & 1) ? FF : 0) + (n >> 1);   // even=gate, odd=up
        } else {
            grow = n0 + row;
        }
        bp[h] = B + (long)e * Bexp + grow * (long)K + cc * 8;
    }

    auto stage = [&](int s, int k0) {
#pragma unroll
        for (int h = 0; h < 2; h++)
            gll16(ap[h] + k0, &As[s][(h * 256 + tid) * 8]);
#pragma unroll
        for (int h = 0; h < BCH; h++)
            gll16(bp[h] + k0, &Bs[s][(h * 256 + tid) * 8]);
    };

    f32x4 acc[4][NJ] = {};
    const int NKI = K / BK;   // 32
    stage(0, 0);
    for (int ki = 0; ki < NKI; ki++) {
        __syncthreads();          // buf[ki&1] loads landed; prior reads of buf[s^1] done
        int s = ki & 1;
        if (ki + 1 < NKI) stage(s ^ 1, (ki + 1) * BK);
        bf16x8 a[4], b[NJ];
#pragma unroll
        for (int i = 0; i < 4; i++)
            a[i] = *(const bf16x8*)&As[s][(mw + i * 16 + r) * BK + sw];
#pragma unroll
        for (int j = 0; j < NJ; j++)
            b[j] = *(const bf16x8*)&Bs[s][(nw + j * 16 + r) * BK + sw];
#pragma unroll
        for (int i = 0; i < 4; i++)
#pragma unroll
            for (int j = 0; j < NJ; j++)
                acc[i][j] = __builtin_amdgcn_mfma_f32_16x16x32_bf16(a[i], b[j], acc[i][j], 0, 0, 0);
    }

    // D layout: row = q*4 + reg, col = lane&15 per 16x16 tile
    if (EPI == 1) {
#pragma unroll
        for (int i = 0; i < 4; i++) {
            long rowb = m0 + mw + i * 16 + q * 4;
#pragma unroll
            for (int j = 0; j < NJ; j++) {
                int n = n0 + nw + j * 16 + r;
#pragma unroll
                for (int reg = 0; reg < 4; reg++) {
                    float v = acc[i][j][reg];
                    float o = __shfl_xor(v, 1);
                    if (!(r & 1)) {
                        float g = v, u = o;
                        float s2 = g / (1.f + __expf(-g)) * u;
                        Cbf[(rowb + reg) * (long)FF + (n >> 1)] = f2bf(s2);
                    }
                }
            }
        }
    } else {
#pragma unroll
        for (int i = 0; i < 4; i++) {
            long rowb = m0 + mw + i * 16 + q * 4;
#pragma unroll
            for (int j = 0; j < NJ; j++) {
                int n = n0 + nw + j * 16 + r;
#pragma unroll
                for (int reg = 0; reg < 4; reg++)
                    Cbf[(rowb + reg) * (long)HID + n] = f2bf(acc[i][j][reg]);
            }
        }
    }
}

// ---------------- weighted combine ----------------
__global__ void combine_kernel(const unsigned short* __restrict__ y,
                               const float* __restrict__ tw,
                               const int* __restrict__ pair_pos,
                               float* __restrict__ out) {
    int t = blockIdx.x;
    int c = threadIdx.x * 4;
    int p0 = pair_pos[t * 2], p1 = pair_pos[t * 2 + 1];
    float w0 = tw[t * 2], w1 = tw[t * 2 + 1];
    ushort4 a = *(const ushort4*)(y + (long)p0 * HID + c);
    ushort4 b = *(const ushort4*)(y + (long)p1 * HID + c);
    float4 o;
    o.x = w0 * bf2f(a.x) + w1 * bf2f(b.x);
    o.y = w0 * bf2f(a.y) + w1 * bf2f(b.y);
    o.z = w0 * bf2f(a.z) + w1 * bf2f(b.z);
    o.w = w0 * bf2f(a.w) + w1 * bf2f(b.w);
    *(float4*)(out + (long)t * HID + c) = o;
}

extern "C" void kernel_launch(void* const* d_in, const int* in_sizes, int n_in,
                              void* d_out, int out_size, void* d_ws, size_t ws_size,
                              hipStream_t stream) {
    const float* hs  = (const float*)d_in[0];
    const float* tw  = (const float*)d_in[1];
    const int*   ids = (const int*)d_in[2];
    const float* wgu = (const float*)d_in[3];
    const float* wdn = (const float*)d_in[4];
    float* out = (float*)d_out;

    char* ws = (char*)d_ws;
    size_t off = 0;
    auto alloc = [&](size_t bytes) -> void* {
        void* p = ws + off;
        off += (bytes + 255) & ~(size_t)255;
        return p;
    };
    unsigned short* wgu_b = (unsigned short*)alloc((size_t)NEXP * 2 * FF * HID * 2); // 32 MB
    unsigned short* wdn_b = (unsigned short*)alloc((size_t)NEXP * HID * FF * 2);     // 16 MB
    unsigned short* hs_b  = (unsigned short*)alloc((size_t)T_TOK * HID * 2);         // 4 MB
    unsigned short* act   = (unsigned short*)alloc((size_t)MAXROWS * FF * 2);        // 10 MB
    unsigned short* ybuf  = (unsigned short*)alloc((size_t)MAXROWS * HID * 2);       // 10 MB
    int* pair_pos = (int*)alloc(NPAIR * 4);
    int* row_tok  = (int*)alloc(MAXROWS * 4);
    int* meta     = (int*)alloc(64);

    prep_kernel<<<NPREP + 1, 256, 0, stream>>>(wgu, hs, ids, pair_pos, row_tok, meta,
                                               wgu_b, hs_b);

    // GEMM1 (+ embedded wdn cvt): (rows x 1024) x wgu_e(2048x1024)^T -> silu -> act
    gemm_moe<1, 256><<<NCVT + 8 * MAX_MT, 256, 0, stream>>>(
        hs_b, wgu_b, act, meta, row_tok, HID, (long)(2 * FF) * HID, wdn, wdn_b);

    // GEMM2: (rows x 1024) x wdn_e(1024 x 1024)^T -> ybuf bf16
    gemm_moe<2, 128><<<8 * MAX_MT, 256, 0, stream>>>(
        act, wdn_b, ybuf, meta, row_tok, FF, (long)HID * FF, nullptr, nullptr);

    combine_kernel<<<T_TOK, 256, 0, stream>>>(ybuf, tw, pair_pos, out);
}